// Round 1
// baseline (960.763 us; speedup 1.0000x reference)
//
#include <hip/hip_runtime.h>
#include <math.h>

// Problem constants (from reference): q (B,T,N,H), k/v (B,S,N,H), mask (B,1,1,S)
constexpr int B = 4;
constexpr int N = 32;
constexpr int H = 128;
constexpr int S = 8192;
constexpr int SPLITS = 8;          // flash-decoding S-splits per (b,n)
constexpr int CH = S / SPLITS;     // 1024 rows per block
constexpr int PARTS = 8;           // 4 waves * 2 half-waves per block
constexpr int WS_STRIDE = H + 2;   // o[128], m, l

// Kernel 1: partial attention over one S-chunk for one (b,n).
// Block = 256 threads = 4 waves; each wave = two independent 32-lane halves.
// Each half processes one K/V row per step: float4 per lane (32*16B = 512B row).
__global__ __launch_bounds__(256) void attn_partial(
    const float* __restrict__ q, const float* __restrict__ k,
    const float* __restrict__ v, const float* __restrict__ mask,
    float* __restrict__ ws)
{
    const int split = blockIdx.x % SPLITS;
    const int bn    = blockIdx.x / SPLITS;   // b*N + n
    const int b     = bn / N;
    const int n     = bn % N;

    const int tid  = threadIdx.x;
    const int wid  = tid >> 6;
    const int lane = tid & 63;
    const int hl   = lane & 31;              // lane within 32-half
    const int part = (wid << 1) | (lane >> 5); // 0..7 partial id

    const float scale = 0.088388347648318447f; // 1/sqrt(128)

    // q fragment: 4 floats per lane covering full H across the 32-half
    const float4 qv = *(const float4*)(q + (size_t)bn * H + hl * 4);
    const float* mrow = mask + (size_t)b * S;

    float  m = -INFINITY;
    float  l = 0.0f;
    float4 o = {0.f, 0.f, 0.f, 0.f};

    const int s_begin = split * CH;
    const int s_end   = s_begin + CH;

    #pragma unroll 4
    for (int s = s_begin + part; s < s_end; s += PARTS) {
        const size_t rowoff = ((size_t)(b * S + s)) * (size_t)(N * H)
                            + (size_t)n * H + (size_t)hl * 4;
        const float4 kv = *(const float4*)(k + rowoff);
        const float4 vv = *(const float4*)(v + rowoff);

        float d = kv.x * qv.x + kv.y * qv.y + kv.z * qv.z + kv.w * qv.w;
        #pragma unroll
        for (int off = 16; off >= 1; off >>= 1)
            d += __shfl_xor(d, off);          // reduce within 32-half

        const float sc = d * scale + mrow[s];
        const float mn = fmaxf(m, sc);
        const float alpha = __expf(m - mn);   // exp(-inf)=0 handles first iter
        const float p     = __expf(sc - mn);
        l   = l * alpha + p;
        o.x = o.x * alpha + p * vv.x;
        o.y = o.y * alpha + p * vv.y;
        o.z = o.z * alpha + p * vv.z;
        o.w = o.w * alpha + p * vv.w;
        m = mn;
    }

    // combine the 8 per-half partials inside the block
    __shared__ float so[PARTS][H];
    __shared__ float sm[PARTS];
    __shared__ float sl[PARTS];
    *(float4*)&so[part][hl * 4] = o;
    if (hl == 0) { sm[part] = m; sl[part] = l; }
    __syncthreads();

    if (tid < H) {
        float M = -INFINITY;
        #pragma unroll
        for (int p = 0; p < PARTS; ++p) M = fmaxf(M, sm[p]);
        float L = 0.f, O = 0.f;
        #pragma unroll
        for (int p = 0; p < PARTS; ++p) {
            const float w = __expf(sm[p] - M);
            L += sl[p] * w;
            O += so[p][tid] * w;
        }
        float* wsp = ws + ((size_t)bn * SPLITS + split) * WS_STRIDE;
        wsp[tid] = O;
        if (tid == 0) { wsp[H] = M; wsp[H + 1] = L; }
    }
}

// Kernel 2: merge SPLITS partials per (b,n), normalize, write out (B,1,N,H).
__global__ __launch_bounds__(128) void attn_combine(
    const float* __restrict__ ws, float* __restrict__ out)
{
    const int bn = blockIdx.x;
    const int h  = threadIdx.x;
    const float* base = ws + (size_t)bn * SPLITS * WS_STRIDE;

    float M = -INFINITY;
    #pragma unroll
    for (int p = 0; p < SPLITS; ++p)
        M = fmaxf(M, base[p * WS_STRIDE + H]);

    float L = 0.f, O = 0.f;
    #pragma unroll
    for (int p = 0; p < SPLITS; ++p) {
        const float w = __expf(base[p * WS_STRIDE + H] - M);
        L += base[p * WS_STRIDE + H + 1] * w;
        O += base[p * WS_STRIDE + h] * w;
    }
    out[(size_t)bn * H + h] = O / L;
}

extern "C" void kernel_launch(void* const* d_in, const int* in_sizes, int n_in,
                              void* d_out, int out_size, void* d_ws, size_t ws_size,
                              hipStream_t stream) {
    const float* q    = (const float*)d_in[0];
    const float* k    = (const float*)d_in[1];
    const float* v    = (const float*)d_in[2];
    const float* mask = (const float*)d_in[3];
    float* out = (float*)d_out;
    float* ws  = (float*)d_ws;   // needs B*N*SPLITS*(H+2)*4 = 532,480 bytes

    attn_partial<<<B * N * SPLITS, 256, 0, stream>>>(q, k, v, mask, ws);
    attn_combine<<<B * N, 128, 0, stream>>>(ws, out);
}